// Round 5
// baseline (88.783 us; speedup 1.0000x reference)
//
#include <hip/hip_runtime.h>

// Problem sizes (fixed)
#define BW    512        // B*W
#define NN    128        // nodes / output cols
#define FF    128        // F
#define HF    512        // H*F
#define ROWS  4          // x-rows per main block
#define MAINB 128        // main blocks
#define ADJR  4          // adjacency rows per block
#define ADJB  32         // adjacency blocks
#define NT    1024       // threads per block

union SMem {
    struct {                       // main path: ~96.5 KB
        float sx   [ROWS][NN];     // x rows
        float smask[ROWS][NN];     // mask rows
        float sh   [ROWS][FF];     // h0 rows
        float srg  [ROWS][HF];     // relu(g)
        float ps   [8 * ROWS * NN];// partial sums (stages 1,2,3)
        float sW   [128][FF + 1];  // gatW chunk, padded (2-way = free)
    } m;
    struct {                       // adjacency: ~81 KB
        float emb[NN][FF + 1];     // padded
        float np [NN][8];
        float nrm[NN];
        float dot[ADJR][2][NN];
        float sim[ADJR][NN];
        int   rnk[2][ADJR][NN];
    } a;
};

__global__ void __launch_bounds__(NT)
fused_kernel(const float* __restrict__ x,
             const float* __restrict__ mask,
             const float* __restrict__ emb,
             const float* __restrict__ gatW,
             const float* __restrict__ fpW,
             const float* __restrict__ fpb,
             const float* __restrict__ opW,
             const float* __restrict__ opb,
             const int*   __restrict__ kptr,
             float* __restrict__ out_main,
             float* __restrict__ out_adj) {
    __shared__ SMem sm;
    const int b = blockIdx.x;
    const int u = threadIdx.x;          // 0..1023

    if (b < MAINB) {
        // =============== MAIN PATH: rows r0..r0+3 ===============
        const int r0 = b * ROWS;

        // prefetch gatW chunk 0 (rows 0..127) into regs — fully coalesced
        const float4* __restrict__ gw4 = (const float4*)gatW;  // 16384 float4
        float4 pf[4];
        #pragma unroll
        for (int it = 0; it < 4; ++it) pf[it] = gw4[it * NT + u];

        // stage 0: x + mask rows -> LDS (coalesced)
        if (u < 512) sm.m.sx[u >> 7][u & 127] = x[r0 * NN + u];
        else         sm.m.smask[(u - 512) >> 7][u & 127] = mask[r0 * NN + (u - 512)];
        __syncthreads();

        // ---- Stage 1: h0 = x @ fpW + fpb   (n split 8 ways, 16 iters)
        {
            const int ng = u >> 7;       // 0..7
            const int o  = u & 127;
            float a0 = 0.f, a1 = 0.f, a2 = 0.f, a3 = 0.f;
            const int n0 = ng * 16;
            #pragma unroll
            for (int nn = 0; nn < 16; ++nn) {
                const int n = n0 + nn;
                const float w = fpW[n * FF + o];          // coalesced
                a0 = fmaf(sm.m.sx[0][n], w, a0);          // broadcast
                a1 = fmaf(sm.m.sx[1][n], w, a1);
                a2 = fmaf(sm.m.sx[2][n], w, a2);
                a3 = fmaf(sm.m.sx[3][n], w, a3);
            }
            float* ps = sm.m.ps;
            ps[(ng * 4 + 0) * NN + o] = a0;
            ps[(ng * 4 + 1) * NN + o] = a1;
            ps[(ng * 4 + 2) * NN + o] = a2;
            ps[(ng * 4 + 3) * NN + o] = a3;
        }
        __syncthreads();
        if (u < 512) {
            const int rr = u >> 7, o = u & 127;
            float s = fpb[o];
            #pragma unroll
            for (int g = 0; g < 8; ++g) s += sm.m.ps[(g * 4 + rr) * NN + o];
            sm.m.sh[rr][o] = s;
        }
        __syncthreads();

        // ---- Stage 2: srg[rr][t] = relu(sum_f sh[rr][f] * gatW[t][f])
        // gatW tiled through LDS in 4 chunks of 128 rows, coalesced loads,
        // register prefetch of next chunk across the barrier.
        for (int tc = 0; tc < 4; ++tc) {
            // store prefetched chunk into sW (padded rows)
            #pragma unroll
            for (int it = 0; it < 4; ++it) {
                const int e4 = it * NT + u;               // 0..4095
                const int row = e4 >> 5, c4 = (e4 & 31) * 4;
                sm.m.sW[row][c4 + 0] = pf[it].x;
                sm.m.sW[row][c4 + 1] = pf[it].y;
                sm.m.sW[row][c4 + 2] = pf[it].z;
                sm.m.sW[row][c4 + 3] = pf[it].w;
            }
            if (tc < 3) {
                #pragma unroll
                for (int it = 0; it < 4; ++it)
                    pf[it] = gw4[(tc + 1) * 4096 + it * NT + u];
            }
            __syncthreads();
            {   // partial dot over 16 f-values per thread group
                const int fq = u >> 7;    // 0..7
                const int tl = u & 127;
                const int f0 = fq * 16;
                float a0 = 0.f, a1 = 0.f, a2 = 0.f, a3 = 0.f;
                #pragma unroll
                for (int ff = 0; ff < 16; ++ff) {
                    const int f = f0 + ff;
                    const float w = sm.m.sW[tl][f];       // 2-way (free)
                    a0 = fmaf(sm.m.sh[0][f], w, a0);      // broadcast
                    a1 = fmaf(sm.m.sh[1][f], w, a1);
                    a2 = fmaf(sm.m.sh[2][f], w, a2);
                    a3 = fmaf(sm.m.sh[3][f], w, a3);
                }
                float* ps = sm.m.ps;
                ps[(fq * 4 + 0) * NN + tl] = a0;
                ps[(fq * 4 + 1) * NN + tl] = a1;
                ps[(fq * 4 + 2) * NN + tl] = a2;
                ps[(fq * 4 + 3) * NN + tl] = a3;
            }
            __syncthreads();
            if (u < 512) {
                const int rr = u >> 7, tl = u & 127;
                float s = 0.f;
                #pragma unroll
                for (int g = 0; g < 8; ++g) s += sm.m.ps[(g * 4 + rr) * NN + tl];
                sm.m.srg[rr][tc * 128 + tl] = fmaxf(s, 0.f);
            }
            __syncthreads();
        }

        // ---- Stage 3: imputed = srg @ opW + opb  (c split 8 ways, 64 iters)
        {
            const int cg = u >> 7;        // 0..7
            const int j  = u & 127;
            float a0 = 0.f, a1 = 0.f, a2 = 0.f, a3 = 0.f;
            const int t0 = cg * 64;
            #pragma unroll 16
            for (int tt = 0; tt < 64; ++tt) {
                const int t = t0 + tt;
                const float w = opW[t * NN + j];          // coalesced
                a0 = fmaf(sm.m.srg[0][t], w, a0);         // broadcast
                a1 = fmaf(sm.m.srg[1][t], w, a1);
                a2 = fmaf(sm.m.srg[2][t], w, a2);
                a3 = fmaf(sm.m.srg[3][t], w, a3);
            }
            float* ps = sm.m.ps;
            ps[(cg * 4 + 0) * NN + j] = a0;
            ps[(cg * 4 + 1) * NN + j] = a1;
            ps[(cg * 4 + 2) * NN + j] = a2;
            ps[(cg * 4 + 3) * NN + j] = a3;
        }
        __syncthreads();
        if (u < 512) {
            const int rr = u >> 7, j = u & 127;
            float val = opb[j];
            #pragma unroll
            for (int g = 0; g < 8; ++g) val += sm.m.ps[(g * 4 + rr) * NN + j];
            const float m = sm.m.smask[rr][j];
            out_main[(r0 + rr) * NN + j] = sm.m.sx[rr][j] * (1.f - m) + val * m;
        }
    } else {
        // =============== ADJACENCY: rows i0..i0+3 ===============
        const int i0 = (b - MAINB) * ADJR;
        const int k  = *kptr;

        // 1) all of emb -> LDS, coalesced float4 (4 iters x 1024 thr x 4 = 16384)
        {
            const float4* __restrict__ e4p = (const float4*)emb;
            #pragma unroll
            for (int it = 0; it < 4; ++it) {
                const int e4 = it * NT + u;               // 0..4095
                const float4 v = e4p[e4];
                const int row = e4 >> 5, c4 = (e4 & 31) * 4;
                sm.a.emb[row][c4 + 0] = v.x;
                sm.a.emb[row][c4 + 1] = v.y;
                sm.a.emb[row][c4 + 2] = v.z;
                sm.a.emb[row][c4 + 3] = v.w;
            }
        }
        __syncthreads();
        // 2) row norms: 8 partials per row
        {
            const int row = u >> 3, part = u & 7;
            const int f0 = part * 16;
            float s = 0.f;
            #pragma unroll
            for (int f = 0; f < 16; ++f) {
                const float e = sm.a.emb[row][f0 + f];
                s = fmaf(e, e, s);
            }
            sm.a.np[row][part] = s;
        }
        __syncthreads();
        if (u < NN) {
            float s = 0.f;
            #pragma unroll
            for (int p = 0; p < 8; ++p) s += sm.a.np[u][p];
            sm.a.nrm[u] = sqrtf(s);
        }
        __syncthreads();
        // 3) normalize in place — ALL 16384 scalars: 16 iters x 1024 threads
        //    (R4 bug: only 4 iters -> rows 32..127 left unnormalized)
        #pragma unroll
        for (int it = 0; it < (NN * FF) / NT; ++it) {     // 16 iters
            const int e = it * NT + u;
            const int row = e >> 7, col = e & 127;
            sm.a.emb[row][col] /= sm.a.nrm[row];
        }
        __syncthreads();
        // 4) partial dots, f split 2 ways
        {
            const int gi = u >> 8;            // 0..3
            const int fh = (u >> 7) & 1;      // 0..1
            const int j  = u & 127;
            const int i  = i0 + gi;
            const int f0 = fh * 64;
            float d = 0.f;
            #pragma unroll
            for (int f = 0; f < 64; ++f)
                d = fmaf(sm.a.emb[i][f0 + f], sm.a.emb[j][f0 + f], d);
            sm.a.dot[gi][fh][j] = d;
        }
        __syncthreads();
        if (u < 512) {
            const int gi = u >> 7, j = u & 127;
            sm.a.sim[gi][j] = sm.a.dot[gi][0][j] + sm.a.dot[gi][1][j];
        }
        __syncthreads();
        // 5) rank, m split 2 ways (jax top_k tie-break: equal -> lower index)
        {
            const int mh = u >> 9;            // 0..1
            const int gi = (u >> 7) & 3;
            const int j  = u & 127;
            const float my = sm.a.sim[gi][j];
            const int m0 = mh * 64;
            int r = 0;
            #pragma unroll
            for (int mm = 0; mm < 64; ++mm) {
                const int m = m0 + mm;
                const float smv = sm.a.sim[gi][m];        // broadcast
                r += (smv > my) | ((smv == my) & (m < j));
            }
            sm.a.rnk[mh][gi][j] = r;
        }
        __syncthreads();
        if (u < 512) {
            const int gi = u >> 7, j = u & 127;
            const int r = sm.a.rnk[0][gi][j] + sm.a.rnk[1][gi][j];
            out_adj[(i0 + gi) * NN + j] = (r < k) ? 1.f : 0.f;
        }
    }
}

extern "C" void kernel_launch(void* const* d_in, const int* in_sizes, int n_in,
                              void* d_out, int out_size, void* d_ws, size_t ws_size,
                              hipStream_t stream) {
    const float* x        = (const float*)d_in[0];  // (8,64,128)
    const float* mask     = (const float*)d_in[1];  // (8,64,128)
    const float* node_emb = (const float*)d_in[2];  // (128,128)
    const float* gat_W    = (const float*)d_in[3];  // (4,128,128)
    // d_in[4] = gat_a — provably unused (softmax over identical logits)
    const float* fp_W     = (const float*)d_in[5];  // (128,128)
    const float* fp_b     = (const float*)d_in[6];  // (128,)
    const float* op_W     = (const float*)d_in[7];  // (512,128)
    const float* op_b     = (const float*)d_in[8];  // (128,)
    const int*   kptr     = (const int*)d_in[9];    // scalar k=30

    float* out_main = (float*)d_out;               // 65536 floats
    float* out_adj  = (float*)d_out + BW * NN;     // 16384 floats

    fused_kernel<<<MAINB + ADJB, NT, 0, stream>>>(
        x, mask, node_emb, gat_W, fp_W, fp_b, op_W, op_b, kptr,
        out_main, out_adj);
}

// Round 6
// 85.730 us; speedup vs baseline: 1.0356x; 1.0356x over previous
//
#include <hip/hip_runtime.h>

// Problem sizes (fixed)
#define BW    512        // B*W
#define NN    128        // nodes / output cols
#define FF    128        // F
#define HF    512        // H*F
#define ROWS  4          // x-rows per main block
#define MAINB 128        // main blocks
#define ADJR  2          // adjacency rows per block
#define ADJB  64         // adjacency blocks
#define NT    512        // threads per block

union SMem {
    struct {                        // main path: 28 KB
        float sxT [NN][4];          // x transposed: sxT[n][rr]   (16B-aligned rows)
        float shT [FF][4];          // h0 transposed: shT[f][rr]
        float srgT[HF][4];          // srgT[t][rr]
        float ps  [8][ROWS][NN];    // partial sums
    } m;
    struct {                        // adjacency: ~72 KB
        float emb[NN][FF + 1];      // padded rows (b32 access, conflict-free)
        float nrm[NN];
        float ps2[ADJR][2][NN];     // dot partials
        float sim[ADJR][NN];        // stride 128 -> 16B-aligned for b128 reads
        int   rnk[2][ADJR][NN];
    } a;
};

__global__ void __launch_bounds__(NT)
fused_kernel(const float* __restrict__ x,
             const float* __restrict__ mask,
             const float* __restrict__ emb,
             const float* __restrict__ gatW,
             const float* __restrict__ fpW,
             const float* __restrict__ fpb,
             const float* __restrict__ opW,
             const float* __restrict__ opb,
             const int*   __restrict__ kptr,
             float* __restrict__ out_main,
             float* __restrict__ out_adj) {
    __shared__ SMem sm;
    const int b = blockIdx.x;
    const int u = threadIdx.x;          // 0..511

    if (b < MAINB) {
        // =============== MAIN PATH: rows r0..r0+3 ===============
        const int r0 = b * ROWS;

        // load x rows -> sxT[n][rr]  (global read coalesced; LDS write one-time)
        {
            const int rr = u >> 7, n = u & 127;
            sm.m.sxT[n][rr] = x[(r0 + rr) * NN + n];
        }
        __syncthreads();

        // ---- Stage 1: h0 = x @ fpW + fpb   (n split 4 ways, 32 iters)
        {
            const int g = u >> 7;        // n-chunk
            const int o = u & 127;
            float a0 = 0.f, a1 = 0.f, a2 = 0.f, a3 = 0.f;
            const int n0 = g * 32;
            #pragma unroll 8
            for (int nn = 0; nn < 32; ++nn) {
                const int n = n0 + nn;
                const float w = fpW[n * FF + o];                   // coalesced
                const float4 sv = *(const float4*)sm.m.sxT[n];     // b128 broadcast
                a0 = fmaf(sv.x, w, a0);
                a1 = fmaf(sv.y, w, a1);
                a2 = fmaf(sv.z, w, a2);
                a3 = fmaf(sv.w, w, a3);
            }
            sm.m.ps[g][0][o] = a0; sm.m.ps[g][1][o] = a1;
            sm.m.ps[g][2][o] = a2; sm.m.ps[g][3][o] = a3;
        }
        __syncthreads();
        {   // reduce -> shT[o][rr]
            const int rr = u >> 7, o = u & 127;
            float s = fpb[o];
            #pragma unroll
            for (int g = 0; g < 4; ++g) s += sm.m.ps[g][rr][o];
            sm.m.shT[o][rr] = s;
        }
        __syncthreads();

        // ---- Stage 2: srgT[t][rr] = relu(sum_f shT[f][rr]*gatW[t][f])
        // 256 active threads, 2 t-cols each (t=u, u+256); others idle (LDS-bound stage)
        if (u < 256) {
            const float4* __restrict__ w1 = (const float4*)(gatW + (size_t)u * FF);
            const float4* __restrict__ w2 = (const float4*)(gatW + (size_t)(u + 256) * FF);
            float b0 = 0.f, b1 = 0.f, b2 = 0.f, b3 = 0.f;
            float c0 = 0.f, c1 = 0.f, c2 = 0.f, c3 = 0.f;
            #pragma unroll 4
            for (int f4 = 0; f4 < FF / 4; ++f4) {
                const float4 q1 = w1[f4];
                const float4 q2 = w2[f4];
                const float4 s0 = *(const float4*)sm.m.shT[f4 * 4 + 0]; // rr0-3 at f
                const float4 s1 = *(const float4*)sm.m.shT[f4 * 4 + 1];
                const float4 s2 = *(const float4*)sm.m.shT[f4 * 4 + 2];
                const float4 s3 = *(const float4*)sm.m.shT[f4 * 4 + 3];
                b0 = fmaf(s0.x, q1.x, fmaf(s1.x, q1.y, fmaf(s2.x, q1.z, fmaf(s3.x, q1.w, b0))));
                b1 = fmaf(s0.y, q1.x, fmaf(s1.y, q1.y, fmaf(s2.y, q1.z, fmaf(s3.y, q1.w, b1))));
                b2 = fmaf(s0.z, q1.x, fmaf(s1.z, q1.y, fmaf(s2.z, q1.z, fmaf(s3.z, q1.w, b2))));
                b3 = fmaf(s0.w, q1.x, fmaf(s1.w, q1.y, fmaf(s2.w, q1.z, fmaf(s3.w, q1.w, b3))));
                c0 = fmaf(s0.x, q2.x, fmaf(s1.x, q2.y, fmaf(s2.x, q2.z, fmaf(s3.x, q2.w, c0))));
                c1 = fmaf(s0.y, q2.x, fmaf(s1.y, q2.y, fmaf(s2.y, q2.z, fmaf(s3.y, q2.w, c1))));
                c2 = fmaf(s0.z, q2.x, fmaf(s1.z, q2.y, fmaf(s2.z, q2.z, fmaf(s3.z, q2.w, c2))));
                c3 = fmaf(s0.w, q2.x, fmaf(s1.w, q2.y, fmaf(s2.w, q2.z, fmaf(s3.w, q2.w, c3))));
            }
            float4* dst1 = (float4*)sm.m.srgT[u];
            float4* dst2 = (float4*)sm.m.srgT[u + 256];
            *dst1 = make_float4(fmaxf(b0, 0.f), fmaxf(b1, 0.f), fmaxf(b2, 0.f), fmaxf(b3, 0.f));
            *dst2 = make_float4(fmaxf(c0, 0.f), fmaxf(c1, 0.f), fmaxf(c2, 0.f), fmaxf(c3, 0.f));
        }
        __syncthreads();

        // ---- Stage 3: imputed = srg @ opW + opb  (t split 8 ways, 2 j-cols/thread)
        {
            const int cg = u >> 6;       // 0..7, wave-uniform
            const int jj = u & 63;
            float a00 = 0.f, a01 = 0.f, a02 = 0.f, a03 = 0.f;
            float a10 = 0.f, a11 = 0.f, a12 = 0.f, a13 = 0.f;
            const int t0 = cg * 64;
            #pragma unroll 8
            for (int tt = 0; tt < 64; ++tt) {
                const int t = t0 + tt;
                const float4 sv = *(const float4*)sm.m.srgT[t]; // b128 broadcast
                const float w0 = opW[t * NN + jj];
                const float w1 = opW[t * NN + jj + 64];
                a00 = fmaf(sv.x, w0, a00); a01 = fmaf(sv.y, w0, a01);
                a02 = fmaf(sv.z, w0, a02); a03 = fmaf(sv.w, w0, a03);
                a10 = fmaf(sv.x, w1, a10); a11 = fmaf(sv.y, w1, a11);
                a12 = fmaf(sv.z, w1, a12); a13 = fmaf(sv.w, w1, a13);
            }
            sm.m.ps[cg][0][jj] = a00; sm.m.ps[cg][1][jj] = a01;
            sm.m.ps[cg][2][jj] = a02; sm.m.ps[cg][3][jj] = a03;
            sm.m.ps[cg][0][jj + 64] = a10; sm.m.ps[cg][1][jj + 64] = a11;
            sm.m.ps[cg][2][jj + 64] = a12; sm.m.ps[cg][3][jj + 64] = a13;
        }
        __syncthreads();
        {   // epilogue: (rr, j)
            const int rr = u >> 7, j = u & 127;
            float val = opb[j];
            #pragma unroll
            for (int g = 0; g < 8; ++g) val += sm.m.ps[g][rr][j];
            const int idx = (r0 + rr) * NN + j;
            const float xv = x[idx];
            const float mv = mask[idx];
            out_main[idx] = fmaf(mv, val - xv, xv);   // x*(1-m)+val*m
        }
    } else {
        // =============== ADJACENCY: rows i0, i0+1 ===============
        const int i0 = (b - MAINB) * ADJR;
        const int k  = *kptr;

        // 1) emb -> LDS, scalar coalesced (bank-conflict-free writes)
        #pragma unroll
        for (int it = 0; it < (NN * FF) / NT; ++it) {   // 32 iters
            const int e = it * NT + u;
            sm.a.emb[e >> 7][e & 127] = emb[e];
        }
        __syncthreads();
        // 2) row norms: 128 threads, one row each (lane=row -> 2-way, free)
        if (u < NN) {
            float s = 0.f;
            #pragma unroll 8
            for (int f = 0; f < FF; ++f) {
                const float e = sm.a.emb[u][f];
                s = fmaf(e, e, s);
            }
            sm.a.nrm[u] = sqrtf(s);
        }
        __syncthreads();
        // 3) raw dots, f split 2 ways:  u -> (g, fs, j)
        {
            const int g  = u >> 8;          // 0..1 (wave-uniform)
            const int fs = (u >> 7) & 1;    // 0..1 (wave-uniform)
            const int j  = u & 127;
            const int i  = i0 + g;
            const int f0 = fs * 64;
            float d = 0.f;
            #pragma unroll 8
            for (int f = 0; f < 64; ++f)
                d = fmaf(sm.a.emb[i][f0 + f], sm.a.emb[j][f0 + f], d);
            sm.a.ps2[g][fs][j] = d;
        }
        __syncthreads();
        // sim = dot/(n_i*n_j)  (vs ref normalize-then-dot: ~1e-8 rel delta,
        // far below the ~1e-3 rank-30/31 sim gap)
        if (u < 256) {
            const int g = u >> 7, j = u & 127;
            const float d = sm.a.ps2[g][0][j] + sm.a.ps2[g][1][j];
            sm.a.sim[g][j] = d / (sm.a.nrm[i0 + g] * sm.a.nrm[j]);
        }
        __syncthreads();
        // 4) rank, m split 2 ways, b128 broadcast reads of sim
        {
            const int g  = u >> 8;          // 0..1
            const int ms = (u >> 7) & 1;    // 0..1
            const int j  = u & 127;
            const float my = sm.a.sim[g][j];
            const int m0 = ms * 64;
            int r = 0;
            #pragma unroll 4
            for (int m4 = 0; m4 < 16; ++m4) {
                const int m = m0 + m4 * 4;
                const float4 sv = *(const float4*)&sm.a.sim[g][m]; // aligned b128
                r += (sv.x > my) | ((sv.x == my) & (m + 0 < j));
                r += (sv.y > my) | ((sv.y == my) & (m + 1 < j));
                r += (sv.z > my) | ((sv.z == my) & (m + 2 < j));
                r += (sv.w > my) | ((sv.w == my) & (m + 3 < j));
            }
            sm.a.rnk[ms][g][j] = r;
        }
        __syncthreads();
        if (u < 256) {
            const int g = u >> 7, j = u & 127;
            const int r = sm.a.rnk[0][g][j] + sm.a.rnk[1][g][j];
            out_adj[(i0 + g) * NN + j] = (r < k) ? 1.f : 0.f;
        }
    }
}

extern "C" void kernel_launch(void* const* d_in, const int* in_sizes, int n_in,
                              void* d_out, int out_size, void* d_ws, size_t ws_size,
                              hipStream_t stream) {
    const float* x        = (const float*)d_in[0];  // (8,64,128)
    const float* mask     = (const float*)d_in[1];  // (8,64,128)
    const float* node_emb = (const float*)d_in[2];  // (128,128)
    const float* gat_W    = (const float*)d_in[3];  // (4,128,128)
    // d_in[4] = gat_a — provably unused (softmax over identical logits)
    const float* fp_W     = (const float*)d_in[5];  // (128,128)
    const float* fp_b     = (const float*)d_in[6];  // (128,)
    const float* op_W     = (const float*)d_in[7];  // (512,128)
    const float* op_b     = (const float*)d_in[8];  // (128,)
    const int*   kptr     = (const int*)d_in[9];    // scalar k=30

    float* out_main = (float*)d_out;               // 65536 floats
    float* out_adj  = (float*)d_out + BW * NN;     // 16384 floats

    fused_kernel<<<MAINB + ADJB, NT, 0, stream>>>(
        x, mask, node_emb, gat_W, fp_W, fp_b, op_W, op_b, kptr,
        out_main, out_adj);
}